// Round 4
// baseline (121.016 us; speedup 1.0000x reference)
//
#include <hip/hip_runtime.h>
#include <hip/hip_bf16.h>

#define NPTS   131072
#define NNODES 2048
#define KSEL   32

// ---- knn decomposition ----
#define TKNN   256                 // threads per knn block
#define PPT    2                   // points per thread = 1 packed f32x2 chain
#define PPG_K  (TKNN * PPT)        // 512 points per knn group
#define NGRP_K (NPTS / PPG_K)      // 256 knn groups
#define NCHUNK 8                   // node chunks; partial-array merge (no atomics)
#define CHN    (NNODES / NCHUNK)   // 256 nodes per chunk
#define HALF   (CHN / 2)           // 128: dual-accumulator split point
// grid = 256*8 = 2048 blocks = 8 blocks/CU = 8 waves/SIMD (full occupancy)

// ---- grouping/scatter decomposition ----
#define GSZ    512                 // points per stability group
#define NG     (NPTS / GSZ)        // 256 groups

typedef unsigned int uint;
typedef unsigned short u16;
typedef unsigned long long u64;
typedef float f2 __attribute__((ext_vector_type(2)));

__device__ __forceinline__ f2 splat(float s) { return (f2){s, s}; }

// order-preserving fp32 -> u32 (handles tiny-negative cancellation results)
__device__ __forceinline__ uint f2ord(float d) {
    uint b = __float_as_uint(d);
    return (b & 0x80000000u) ? ~b : (b | 0x80000000u);
}
__device__ __forceinline__ float ord2f(uint t) {
    uint b = (t & 0x80000000u) ? (t ^ 0x80000000u) : ~t;
    return __uint_as_float(b);
}

// --- K1: partial 1-NN, 2 pts/thread as 1 packed-f32 chain (v_pk_* VOP3P) ---
// Node chunk is self-packed into 4KB LDS (one node/thread, same |n|^2 rounding
// as before -> deterministic, bit-identical across blocks). Main loop reads
// sn4[jj] with wave-uniform address -> broadcast ds_read_b128, conflict-free.
// Distance per half-lane: m = nx*x; t = fma(ny,y,m); r = fma(nz,z,t); d=(pp+r)+nn
// (bit-identical sequence to prior accepted versions).
// Dual-half quad-deferred argmin (unchanged): 4 independent min3 chains/thread;
// strict-improvement quad base preserves first occurrence; endgame recomputes
// the winning quad with the identical op sequence and takes the first match.
// NEW: result goes to part[c*NPTS+pid] via plain coalesced store (one writer
// per slot, no init, no atomics); merge_hist min-reduces the 8 partials.
__global__ __launch_bounds__(256, 8) void knn_part(const float* __restrict__ pts,
                                                   const float* __restrict__ nodes,
                                                   u64* __restrict__ part) {
    __shared__ float4 sn4[CHN];              // 4 KB
    int bid = blockIdx.x;
    int c   = bid & (NCHUNK - 1);            // block-uniform chunk
    int g   = bid >> 3;                      // knn point group
    int t   = threadIdx.x;

    // pack this chunk's nodes into LDS (1 node per thread)
    {
        int n = c * CHN + t;
        float x = nodes[3 * n], y = nodes[3 * n + 1], z = nodes[3 * n + 2];
        // |n|^2 with numpy's mul-then-add rounding
        float nn = __fadd_rn(__fadd_rn(__fmul_rn(x, x), __fmul_rn(y, y)),
                             __fmul_rn(z, z));
        sn4[t] = make_float4(x, y, z, nn);
    }

    // load 2 points, pack into 1 chain: lane-half h holds point h
    f2 pp2, nx2, ny2, nz2;
    #pragma unroll
    for (int h = 0; h < 2; ++h) {
        int pid = g * PPG_K + h * TKNN + t;
        float p0 = pts[3 * pid], p1 = pts[3 * pid + 1], p2 = pts[3 * pid + 2];
        float pp = __fadd_rn(__fadd_rn(__fmul_rn(p0, p0), __fmul_rn(p1, p1)),
                             __fmul_rn(p2, p2));
        pp2[h] = pp;
        nx2[h] = __fmul_rn(-2.0f, p0);   // exact
        ny2[h] = __fmul_rn(-2.0f, p1);
        nz2[h] = __fmul_rn(-2.0f, p2);
    }
    __syncthreads();

    float bestA[PPT], bestB[PPT];
    int   qbA[PPT],   qbB[PPT];
    #pragma unroll
    for (int p = 0; p < PPT; ++p) {
        bestA[p] = 3.4e38f; bestB[p] = 3.4e38f; qbA[p] = 0; qbB[p] = 0;
    }

    #pragma unroll 2
    for (int jj = 0; jj < HALF; jj += 4) {
        float4 a0 = sn4[jj + 0];             // uniform addr -> broadcast ds_read_b128
        float4 a1 = sn4[jj + 1];
        float4 a2 = sn4[jj + 2];
        float4 a3 = sn4[jj + 3];
        float4 b0 = sn4[HALF + jj + 0];
        float4 b1 = sn4[HALF + jj + 1];
        float4 b2 = sn4[HALF + jj + 2];
        float4 b3 = sn4[HALF + jj + 3];

        f2 dA0, dA1, dA2, dA3, dB0, dB1, dB2, dB3;
        {   f2 m = nx2 * splat(a0.x);
            f2 r = __builtin_elementwise_fma(ny2, splat(a0.y), m);
            r    = __builtin_elementwise_fma(nz2, splat(a0.z), r);
            dA0  = (pp2 + r) + splat(a0.w); }
        {   f2 m = nx2 * splat(a1.x);
            f2 r = __builtin_elementwise_fma(ny2, splat(a1.y), m);
            r    = __builtin_elementwise_fma(nz2, splat(a1.z), r);
            dA1  = (pp2 + r) + splat(a1.w); }
        {   f2 m = nx2 * splat(a2.x);
            f2 r = __builtin_elementwise_fma(ny2, splat(a2.y), m);
            r    = __builtin_elementwise_fma(nz2, splat(a2.z), r);
            dA2  = (pp2 + r) + splat(a2.w); }
        {   f2 m = nx2 * splat(a3.x);
            f2 r = __builtin_elementwise_fma(ny2, splat(a3.y), m);
            r    = __builtin_elementwise_fma(nz2, splat(a3.z), r);
            dA3  = (pp2 + r) + splat(a3.w); }
        {   f2 m = nx2 * splat(b0.x);
            f2 r = __builtin_elementwise_fma(ny2, splat(b0.y), m);
            r    = __builtin_elementwise_fma(nz2, splat(b0.z), r);
            dB0  = (pp2 + r) + splat(b0.w); }
        {   f2 m = nx2 * splat(b1.x);
            f2 r = __builtin_elementwise_fma(ny2, splat(b1.y), m);
            r    = __builtin_elementwise_fma(nz2, splat(b1.z), r);
            dB1  = (pp2 + r) + splat(b1.w); }
        {   f2 m = nx2 * splat(b2.x);
            f2 r = __builtin_elementwise_fma(ny2, splat(b2.y), m);
            r    = __builtin_elementwise_fma(nz2, splat(b2.z), r);
            dB2  = (pp2 + r) + splat(b2.w); }
        {   f2 m = nx2 * splat(b3.x);
            f2 r = __builtin_elementwise_fma(ny2, splat(b3.y), m);
            r    = __builtin_elementwise_fma(nz2, splat(b3.z), r);
            dB3  = (pp2 + r) + splat(b3.w); }

        #pragma unroll
        for (int p = 0; p < PPT; ++p) {
            float eA0 = p ? dA0.y : dA0.x;
            float eA1 = p ? dA1.y : dA1.x;
            float eA2 = p ? dA2.y : dA2.x;
            float eA3 = p ? dA3.y : dA3.x;
            float mA  = fminf(fminf(bestA[p], eA0), eA1);   // v_min3_f32
            float nA  = fminf(fminf(mA, eA2), eA3);         // v_min3_f32
            qbA[p]    = (nA < bestA[p]) ? jj : qbA[p];      // strict: first quad wins
            bestA[p]  = nA;

            float eB0 = p ? dB0.y : dB0.x;
            float eB1 = p ? dB1.y : dB1.x;
            float eB2 = p ? dB2.y : dB2.x;
            float eB3 = p ? dB3.y : dB3.x;
            float mB  = fminf(fminf(bestB[p], eB0), eB1);
            float nB  = fminf(fminf(mB, eB2), eB3);
            qbB[p]    = (nB < bestB[p]) ? jj : qbB[p];      // relative to HALF
            bestB[p]  = nB;
        }
    }

    // endgame: merge halves (tie -> A = smaller node indices), recover exact
    // node index within the winning quad, plain store of this chunk's partial
    #pragma unroll
    for (int p = 0; p < PPT; ++p) {
        float bA = bestA[p], bB = bestB[p];
        float b  = fminf(bA, bB);                 // exact IEEE min
        int base = (bB < bA) ? (HALF + qbB[p]) : qbA[p];

        float nx = nx2[p], ny = ny2[p], nz = nz2[p], pp = pp2[p];
        float dd[4];
        #pragma unroll
        for (int o = 0; o < 4; ++o) {
            float4 v = sn4[base + o];        // per-lane LDS gather, tiny count
            float m = __fmul_rn(nx, v.x);
            float r = __builtin_fmaf(ny, v.y, m);
            r       = __builtin_fmaf(nz, v.z, r);
            dd[o]   = __fadd_rn(__fadd_rn(pp, r), v.w);   // bit-identical to pk path
        }
        int off = 3;                          // descending chain -> first match wins
        if (dd[2] == b) off = 2;
        if (dd[1] == b) off = 1;
        if (dd[0] == b) off = 0;

        int pid = g * PPG_K + p * TKNN + t;
        u64 key = ((u64)f2ord(b) << 32) | (uint)(c * CHN + base + off);
        part[(size_t)c * NPTS + pid] = key;   // one writer per slot, coalesced
    }
}

// --- K2: 8-way u64 min-reduce partials, decode, write d2/id/pcd, histogram ---
__global__ __launch_bounds__(256) void merge_hist(const u64* __restrict__ part,
                                                  float* __restrict__ out_d2,
                                                  float* __restrict__ out_id,
                                                  int* __restrict__ pcd,
                                                  u16* __restrict__ hist16,
                                                  float* __restrict__ patch) {
    __shared__ uint lh[NNODES];
    int g = blockIdx.x, t = threadIdx.x;
    patch[(size_t)g * 256 + t] = 0.0f;       // 256x256 = full 65536-float patch zeroed
    for (int i = t; i < NNODES; i += 256) lh[i] = 0;
    __syncthreads();

    #pragma unroll
    for (int q = 0; q < GSZ / 256; ++q) {
        int pid = g * GSZ + q * 256 + t;
        u64 key = part[pid];                 // chunk 0
        #pragma unroll
        for (int cc = 1; cc < NCHUNK; ++cc) {
            u64 k2 = part[(size_t)cc * NPTS + pid];   // coalesced per plane
            key = (k2 < key) ? k2 : key;     // min key == (min d2, then min node)
        }
        uint bi = (uint)key;                 // low 32: node index
        float d = ord2f((uint)(key >> 32));  // exact d2 decode
        atomicAdd(&lh[bi], 1u);
        out_d2[pid] = d;
        out_id[pid] = (float)bi;             // exact: bi < 2^24
        pcd[pid]    = (int)bi;
    }
    __syncthreads();
    for (int i = t; i < NNODES; i += 256)
        hist16[(size_t)g * NNODES + i] = (u16)lh[i];   // contiguous stores
}

// --- K3: per-node exclusive prefix across the 256 groups; offs in [node][group] ---
__global__ __launch_bounds__(256) void scan_offs(const u16* __restrict__ hist16,
                                                 uint* __restrict__ offs) {
    int t = threadIdx.x, lane = t & 63, wv = t >> 6;
    int node = blockIdx.x * 4 + wv;

    uint v0 = hist16[(size_t)(4 * lane + 0) * NNODES + node];
    uint v1 = hist16[(size_t)(4 * lane + 1) * NNODES + node];
    uint v2 = hist16[(size_t)(4 * lane + 2) * NNODES + node];
    uint v3 = hist16[(size_t)(4 * lane + 3) * NNODES + node];
    uint s = v0 + v1 + v2 + v3;
    uint a = s;
    #pragma unroll
    for (int d = 1; d < 64; d <<= 1) {
        uint y = __shfl_up(a, d, 64);
        if (lane >= d) a += y;
    }
    uint base = a - s;                        // exclusive across lanes
    uint4 o = make_uint4(base, base + v0, base + v0 + v1, base + v0 + v1 + v2);
    *(uint4*)(offs + (size_t)node * NG + 4 * lane) = o;   // contiguous 16B store
}

// --- K4: stable scatter of first-32 point indices per node ---
__global__ __launch_bounds__(256) void scatter_patch(const int* __restrict__ pcd,
                                                     const uint* __restrict__ offs,
                                                     float* __restrict__ patch) {
    __shared__ int ids[GSZ];
    int g = blockIdx.x, t = threadIdx.x;
    ids[t]       = pcd[g * GSZ + t];
    ids[256 + t] = pcd[g * GSZ + 256 + t];
    __syncthreads();

    int i0 = t, i1 = 256 + t;
    int my0 = ids[i0], my1 = ids[i1];
    int r0 = 0, r1 = 0;
    #pragma unroll 8
    for (int j = 0; j < GSZ; ++j) {
        int id = ids[j];                      // broadcast LDS read, conflict-free
        r0 += (j < i0 && id == my0) ? 1 : 0;
        r1 += (j < i1 && id == my1) ? 1 : 0;
    }
    uint rk0 = offs[(size_t)my0 * NG + g] + (uint)r0;
    uint rk1 = offs[(size_t)my1 * NG + g] + (uint)r1;
    if (rk0 < KSEL) patch[(size_t)my0 * KSEL + rk0] = (float)(g * GSZ + i0);
    if (rk1 < KSEL) patch[(size_t)my1 * KSEL + rk1] = (float)(g * GSZ + i1);
}

extern "C" void kernel_launch(void* const* d_in, const int* in_sizes, int n_in,
                              void* d_out, int out_size, void* d_ws, size_t ws_size,
                              hipStream_t stream) {
    const float* pts   = (const float*)d_in[0];
    const float* nodes = (const float*)d_in[1];

    float* out       = (float*)d_out;
    float* out_d2    = out;                  // 131072 floats
    float* out_id    = out + NPTS;           // 131072 floats
    float* out_patch = out + 2 * NPTS;       // 65536 floats

    // workspace: 11.5 MB
    char* ws = (char*)d_ws;
    u64*   part   = (u64*) ws;                               // 8 MB  (8 x 131072 u64)
    u16*   hist16 = (u16*) (ws + (8 << 20));                 // 1 MB  (256 x 2048 u16)
    uint*  offs   = (uint*) (ws + (9 << 20));                // 2 MB  (2048 x 256 u32)
    int*   pcd    = (int*)  (ws + (11 << 20));               // 512 KB

    knn_part<<<NGRP_K * NCHUNK, TKNN, 0, stream>>>(pts, nodes, part);
    merge_hist<<<NG, 256, 0, stream>>>(part, out_d2, out_id, pcd, hist16, out_patch);
    scan_offs<<<NNODES / 4, 256, 0, stream>>>(hist16, offs);
    scatter_patch<<<NG, 256, 0, stream>>>(pcd, offs, out_patch);
}

// Round 7
// 119.235 us; speedup vs baseline: 1.0149x; 1.0149x over previous
//
#include <hip/hip_runtime.h>
#include <hip/hip_bf16.h>

#define NPTS   131072
#define NNODES 2048
#define KSEL   32

// ---- knn decomposition ----
#define TKNN   256                 // threads per knn block
#define PPT    2                   // points per thread = 1 packed f32x2 chain
#define PPG_K  (TKNN * PPT)        // 512 points per knn group
#define NGRP_K (NPTS / PPG_K)      // 256 knn groups
#define NCHUNK 8                   // node chunks; partial-array merge (no atomics)
#define CHN    (NNODES / NCHUNK)   // 256 nodes per chunk
#define HALF   (CHN / 2)           // 128: dual-accumulator split point
// grid = 256*8 = 2048 blocks = 8 blocks/CU

// ---- grouping/scatter decomposition ----
#define GSZ    512                 // points per stability group
#define NG     (NPTS / GSZ)        // 256 groups

typedef unsigned int uint;
typedef unsigned short u16;
typedef unsigned long long u64;
typedef float f2 __attribute__((ext_vector_type(2)));

__device__ __forceinline__ f2 splat(float s) { return (f2){s, s}; }

// order-preserving fp32 -> u32 (handles tiny-negative cancellation results)
__device__ __forceinline__ uint f2ord(float d) {
    uint b = __float_as_uint(d);
    return (b & 0x80000000u) ? ~b : (b | 0x80000000u);
}
__device__ __forceinline__ float ord2f(uint t) {
    uint b = (t & 0x80000000u) ? (t ^ 0x80000000u) : ~t;
    return __uint_as_float(b);
}

// --- K0: pack nodes {x,y,z,|n|^2} (8 blocks) --- [proven R1]
__global__ __launch_bounds__(256) void prep_nodes(const float* __restrict__ nodes,
                                                  float4* __restrict__ n4) {
    int i = blockIdx.x * 256 + threadIdx.x;
    float x = nodes[3 * i], y = nodes[3 * i + 1], z = nodes[3 * i + 2];
    // |n|^2 with numpy's mul-then-add rounding
    float nn = __fadd_rn(__fadd_rn(__fmul_rn(x, x), __fmul_rn(y, y)), __fmul_rn(z, z));
    n4[i] = make_float4(x, y, z, nn);
}

// --- K1: partial 1-NN, 2 pts/thread as 1 packed-f32 chain (v_pk_* VOP3P) ---
// [structure proven R3; store path proven R4]
// Node operands via block-uniform global reads -> s_load into SGPRs.
// Distance per half-lane: m = nx*x; t = fma(ny,y,m); r = fma(nz,z,t); d=(pp+r)+nn
// (bit-identical sequence to prior accepted versions).
// Dual-half quad-deferred argmin: chunk split into nodes [0,HALF) and [HALF,CHN);
// each point keeps independent (best,qb) per half -> 4 independent loop-carried
// min3 chains per thread. Strict-improvement quad base preserves first
// occurrence; merge tie -> half A (lower node indices). Endgame recomputes the
// winning quad with the identical op sequence and takes the first exact match.
// Result goes to part[c*NPTS+pid] via plain coalesced store (one writer per
// slot, no init, no atomics); merge_hist min-reduces the 8 partials.
__global__ __launch_bounds__(256) void knn_part(const float* __restrict__ pts,
                                                const float4* __restrict__ n4,
                                                u64* __restrict__ part) {
    int bid = blockIdx.x;
    int c   = bid & (NCHUNK - 1);            // block-uniform chunk
    int g   = bid >> 3;                      // knn point group
    int t   = threadIdx.x;

    // load 2 points, pack into 1 chain: lane-half h holds point h
    f2 pp2, nx2, ny2, nz2;
    #pragma unroll
    for (int h = 0; h < 2; ++h) {
        int pid = g * PPG_K + h * TKNN + t;
        float p0 = pts[3 * pid], p1 = pts[3 * pid + 1], p2 = pts[3 * pid + 2];
        float pp = __fadd_rn(__fadd_rn(__fmul_rn(p0, p0), __fmul_rn(p1, p1)),
                             __fmul_rn(p2, p2));
        pp2[h] = pp;
        nx2[h] = __fmul_rn(-2.0f, p0);   // exact
        ny2[h] = __fmul_rn(-2.0f, p1);
        nz2[h] = __fmul_rn(-2.0f, p2);
    }

    const float4* np = n4 + c * CHN;         // block-uniform base -> scalar s_load
    float bestA[PPT], bestB[PPT];
    int   qbA[PPT],   qbB[PPT];
    #pragma unroll
    for (int p = 0; p < PPT; ++p) {
        bestA[p] = 3.4e38f; bestB[p] = 3.4e38f; qbA[p] = 0; qbB[p] = 0;
    }

    #pragma unroll 2
    for (int jj = 0; jj < HALF; jj += 4) {
        float4 a0 = np[jj + 0];              // uniform addr -> s_load_dwordx16
        float4 a1 = np[jj + 1];
        float4 a2 = np[jj + 2];
        float4 a3 = np[jj + 3];
        float4 b0 = np[HALF + jj + 0];
        float4 b1 = np[HALF + jj + 1];
        float4 b2 = np[HALF + jj + 2];
        float4 b3 = np[HALF + jj + 3];

        f2 dA0, dA1, dA2, dA3, dB0, dB1, dB2, dB3;
        {   f2 m = nx2 * splat(a0.x);
            f2 r = __builtin_elementwise_fma(ny2, splat(a0.y), m);
            r    = __builtin_elementwise_fma(nz2, splat(a0.z), r);
            dA0  = (pp2 + r) + splat(a0.w); }
        {   f2 m = nx2 * splat(a1.x);
            f2 r = __builtin_elementwise_fma(ny2, splat(a1.y), m);
            r    = __builtin_elementwise_fma(nz2, splat(a1.z), r);
            dA1  = (pp2 + r) + splat(a1.w); }
        {   f2 m = nx2 * splat(a2.x);
            f2 r = __builtin_elementwise_fma(ny2, splat(a2.y), m);
            r    = __builtin_elementwise_fma(nz2, splat(a2.z), r);
            dA2  = (pp2 + r) + splat(a2.w); }
        {   f2 m = nx2 * splat(a3.x);
            f2 r = __builtin_elementwise_fma(ny2, splat(a3.y), m);
            r    = __builtin_elementwise_fma(nz2, splat(a3.z), r);
            dA3  = (pp2 + r) + splat(a3.w); }
        {   f2 m = nx2 * splat(b0.x);
            f2 r = __builtin_elementwise_fma(ny2, splat(b0.y), m);
            r    = __builtin_elementwise_fma(nz2, splat(b0.z), r);
            dB0  = (pp2 + r) + splat(b0.w); }
        {   f2 m = nx2 * splat(b1.x);
            f2 r = __builtin_elementwise_fma(ny2, splat(b1.y), m);
            r    = __builtin_elementwise_fma(nz2, splat(b1.z), r);
            dB1  = (pp2 + r) + splat(b1.w); }
        {   f2 m = nx2 * splat(b2.x);
            f2 r = __builtin_elementwise_fma(ny2, splat(b2.y), m);
            r    = __builtin_elementwise_fma(nz2, splat(b2.z), r);
            dB2  = (pp2 + r) + splat(b2.w); }
        {   f2 m = nx2 * splat(b3.x);
            f2 r = __builtin_elementwise_fma(ny2, splat(b3.y), m);
            r    = __builtin_elementwise_fma(nz2, splat(b3.z), r);
            dB3  = (pp2 + r) + splat(b3.w); }

        #pragma unroll
        for (int p = 0; p < PPT; ++p) {
            float eA0 = p ? dA0.y : dA0.x;
            float eA1 = p ? dA1.y : dA1.x;
            float eA2 = p ? dA2.y : dA2.x;
            float eA3 = p ? dA3.y : dA3.x;
            float mA  = fminf(fminf(bestA[p], eA0), eA1);   // v_min3_f32
            float nA  = fminf(fminf(mA, eA2), eA3);         // v_min3_f32
            qbA[p]    = (nA < bestA[p]) ? jj : qbA[p];      // strict: first quad wins
            bestA[p]  = nA;

            float eB0 = p ? dB0.y : dB0.x;
            float eB1 = p ? dB1.y : dB1.x;
            float eB2 = p ? dB2.y : dB2.x;
            float eB3 = p ? dB3.y : dB3.x;
            float mB  = fminf(fminf(bestB[p], eB0), eB1);
            float nB  = fminf(fminf(mB, eB2), eB3);
            qbB[p]    = (nB < bestB[p]) ? jj : qbB[p];      // relative to HALF
            bestB[p]  = nB;
        }
    }

    // endgame: merge halves (tie -> A = smaller node indices), recover exact
    // node index within the winning quad, plain store of this chunk's partial
    #pragma unroll
    for (int p = 0; p < PPT; ++p) {
        float bA = bestA[p], bB = bestB[p];
        float b  = fminf(bA, bB);                 // exact IEEE min
        int base = (bB < bA) ? (HALF + qbB[p]) : qbA[p];

        float nx = nx2[p], ny = ny2[p], nz = nz2[p], pp = pp2[p];
        float dd[4];
        #pragma unroll
        for (int o = 0; o < 4; ++o) {
            float4 v = np[base + o];         // per-lane addr, L2-hot (32 KB table)
            float m = __fmul_rn(nx, v.x);
            float r = __builtin_fmaf(ny, v.y, m);
            r       = __builtin_fmaf(nz, v.z, r);
            dd[o]   = __fadd_rn(__fadd_rn(pp, r), v.w);   // bit-identical to pk path
        }
        int off = 3;                          // descending chain -> first match wins
        if (dd[2] == b) off = 2;
        if (dd[1] == b) off = 1;
        if (dd[0] == b) off = 0;

        int pid = g * PPG_K + p * TKNN + t;
        u64 key = ((u64)f2ord(b) << 32) | (uint)(c * CHN + base + off);
        part[(size_t)c * NPTS + pid] = key;   // one writer per slot, coalesced
    }
}

// --- K2: 8-way u64 min-reduce partials, decode, write d2/id/pcd, histogram ---
// [proven R4]
__global__ __launch_bounds__(256) void merge_hist(const u64* __restrict__ part,
                                                  float* __restrict__ out_d2,
                                                  float* __restrict__ out_id,
                                                  int* __restrict__ pcd,
                                                  u16* __restrict__ hist16,
                                                  float* __restrict__ patch) {
    __shared__ uint lh[NNODES];
    int g = blockIdx.x, t = threadIdx.x;
    patch[(size_t)g * 256 + t] = 0.0f;       // 256x256 = full 65536-float patch zeroed
    for (int i = t; i < NNODES; i += 256) lh[i] = 0;
    __syncthreads();

    #pragma unroll
    for (int q = 0; q < GSZ / 256; ++q) {
        int pid = g * GSZ + q * 256 + t;
        u64 key = part[pid];                 // chunk 0
        #pragma unroll
        for (int cc = 1; cc < NCHUNK; ++cc) {
            u64 k2 = part[(size_t)cc * NPTS + pid];   // coalesced per plane
            key = (k2 < key) ? k2 : key;     // min key == (min d2, then min node)
        }
        uint bi = (uint)key;                 // low 32: node index
        float d = ord2f((uint)(key >> 32));  // exact d2 decode
        atomicAdd(&lh[bi], 1u);
        out_d2[pid] = d;
        out_id[pid] = (float)bi;             // exact: bi < 2^24
        pcd[pid]    = (int)bi;
    }
    __syncthreads();
    for (int i = t; i < NNODES; i += 256)
        hist16[(size_t)g * NNODES + i] = (u16)lh[i];   // contiguous stores
}

// --- K3: per-node exclusive prefix across the 256 groups; offs in [node][group] ---
__global__ __launch_bounds__(256) void scan_offs(const u16* __restrict__ hist16,
                                                 uint* __restrict__ offs) {
    int t = threadIdx.x, lane = t & 63, wv = t >> 6;
    int node = blockIdx.x * 4 + wv;

    uint v0 = hist16[(size_t)(4 * lane + 0) * NNODES + node];
    uint v1 = hist16[(size_t)(4 * lane + 1) * NNODES + node];
    uint v2 = hist16[(size_t)(4 * lane + 2) * NNODES + node];
    uint v3 = hist16[(size_t)(4 * lane + 3) * NNODES + node];
    uint s = v0 + v1 + v2 + v3;
    uint a = s;
    #pragma unroll
    for (int d = 1; d < 64; d <<= 1) {
        uint y = __shfl_up(a, d, 64);
        if (lane >= d) a += y;
    }
    uint base = a - s;                        // exclusive across lanes
    uint4 o = make_uint4(base, base + v0, base + v0 + v1, base + v0 + v1 + v2);
    *(uint4*)(offs + (size_t)node * NG + 4 * lane) = o;   // contiguous 16B store
}

// --- K4: stable scatter of first-32 point indices per node ---
__global__ __launch_bounds__(256) void scatter_patch(const int* __restrict__ pcd,
                                                     const uint* __restrict__ offs,
                                                     float* __restrict__ patch) {
    __shared__ int ids[GSZ];
    int g = blockIdx.x, t = threadIdx.x;
    ids[t]       = pcd[g * GSZ + t];
    ids[256 + t] = pcd[g * GSZ + 256 + t];
    __syncthreads();

    int i0 = t, i1 = 256 + t;
    int my0 = ids[i0], my1 = ids[i1];
    int r0 = 0, r1 = 0;
    #pragma unroll 8
    for (int j = 0; j < GSZ; ++j) {
        int id = ids[j];                      // broadcast LDS read, conflict-free
        r0 += (j < i0 && id == my0) ? 1 : 0;
        r1 += (j < i1 && id == my1) ? 1 : 0;
    }
    uint rk0 = offs[(size_t)my0 * NG + g] + (uint)r0;
    uint rk1 = offs[(size_t)my1 * NG + g] + (uint)r1;
    if (rk0 < KSEL) patch[(size_t)my0 * KSEL + rk0] = (float)(g * GSZ + i0);
    if (rk1 < KSEL) patch[(size_t)my1 * KSEL + rk1] = (float)(g * GSZ + i1);
}

extern "C" void kernel_launch(void* const* d_in, const int* in_sizes, int n_in,
                              void* d_out, int out_size, void* d_ws, size_t ws_size,
                              hipStream_t stream) {
    const float* pts   = (const float*)d_in[0];
    const float* nodes = (const float*)d_in[1];

    float* out       = (float*)d_out;
    float* out_d2    = out;                  // 131072 floats
    float* out_id    = out + NPTS;           // 131072 floats
    float* out_patch = out + 2 * NPTS;       // 65536 floats

    // workspace: ~11.6 MB (layout proven R4)
    char* ws = (char*)d_ws;
    u64*   part   = (u64*) ws;                               // 8 MB  (8 x 131072 u64)
    u16*   hist16 = (u16*) (ws + (8 << 20));                 // 1 MB  (256 x 2048 u16)
    uint*  offs   = (uint*) (ws + (9 << 20));                // 2 MB  (2048 x 256 u32)
    int*   pcd    = (int*)  (ws + (11 << 20));               // 512 KB
    float4* n4    = (float4*)(ws + (11 << 20) + (512 << 10));// 32 KB

    prep_nodes<<<NNODES / 256, 256, 0, stream>>>(nodes, n4);
    knn_part<<<NGRP_K * NCHUNK, TKNN, 0, stream>>>(pts, n4, part);
    merge_hist<<<NG, 256, 0, stream>>>(part, out_d2, out_id, pcd, hist16, out_patch);
    scan_offs<<<NNODES / 4, 256, 0, stream>>>(hist16, offs);
    scatter_patch<<<NG, 256, 0, stream>>>(pcd, offs, out_patch);
}